// Round 8
// baseline (96.395 us; speedup 1.0000x reference)
//
#include <hip/hip_runtime.h>

#define FR 3
#define KS 7
#define TLX 64
#define TLY 8
#define PPT 2                 // consecutive pixel rows per thread
#define HX (TLX + 2*FR)       // 70
#define HY (TLY + FR)         // 11 (top halo only; half-kernel has dy<=0)
#define IMG_H 512
#define IMG_W 512
#define NB 8
#define NC 3
#define GXB (IMG_W / TLX)     // 8
#define GYB (IMG_H / TLY)     // 64
#define NMAIN (GXB * GYB * NB)    // 4096
#define RIM_PER_IMG 6108          // 512^2 - 506^2
#define NRIM_THREADS (RIM_PER_IMG * NB)          // 48864
#define NRIM_BLK ((NRIM_THREADS + 255) / 256)    // 191
#define NBLK_A (NMAIN + NRIM_BLK)                // 4287
#define NPART NBLK_A

// exp(-50*s) = 2^(-K2*s), K2 = 50*log2(e)=72.13475204444817. Main kernel
// pre-scales inputs by K=sqrt(K2) so exp2 arg is just -(sum of squared diffs).
#define KSC 8.493218f
#define K2F 72.134752f

constexpr double g1d[KS] = {0.011108996538242306, 0.1353352832366127,
                            0.6065306597126334,   1.0,
                            0.6065306597126334,   0.1353352832366127,
                            0.011108996538242306};
constexpr double SUMG = 1.0 + 2.0 * (0.011108996538242306 + 0.1353352832366127
                                     + 0.6065306597126334);
constexpr double INVN = 1.0 / (SUMG * SUMG);
constexpr double KD   = 8.493218;   // must match KSC
constexpr double WPAIR = 2.0 * INVN / KD;   // pair-doubled, un-scaled, normalized

__device__ __forceinline__ int refl(int i, int n) {
    i = (i < 0) ? -i : i;
    return (i >= n) ? (2*n - 2 - i) : i;
}

// Fused kernel. Blocks [0, NRIM_BLK) = rim path (latency-bound, scheduled first);
// blocks [NRIM_BLK, NBLK_A) = main path.
// Main path: pixels packed as float4{R,G,B,0} in LDS -> each tap is ONE
// ds_read_b128 at a compile-time immediate offset (zero per-tap address VALU).
// LDS = 12.3 KB -> 8 blocks/CU = 32 waves/CU.
__global__ __launch_bounds__(256) void blt_fused(const float* __restrict__ in,
                                                 float* __restrict__ partial) {
    __shared__ float4 smv[HY * HX];      // 11*70*16 = 12320 B
    __shared__ float wsum[4];
    const int tid = threadIdx.x;
    float a = 0.0f;

    if (blockIdx.x >= NRIM_BLK) {
        // ---- main path ----
        const int bid = blockIdx.x - NRIM_BLK;
        const int b   = bid >> 9;            // 512 blocks per image (8 x 64)
        const int rem = bid & 511;
        const int by  = (rem >> 3) * TLY;
        const int bx  = (rem & 7) * TLX;
        const int tx  = tid & 63;            // column within tile (one per lane)
        const int ty  = tid >> 6;            // 0..3 -> 2-row strip (wave-uniform)
        const float* base = in + (size_t)b * NC * IMG_H * IMG_W;

        // Stage reflect-padded halo tile as packed float4{R,G,B,0}, pre-scaled.
        for (int idx = tid; idx < HY * HX; idx += 256) {
            int ly = idx / HX;
            int lx = idx - ly * HX;
            int gy = refl(by + ly - FR, IMG_H);
            int gx = refl(bx + lx - FR, IMG_W);
            float4 p;
            p.x = base[(0 * IMG_H + gy) * IMG_W + gx] * KSC;
            p.y = base[(1 * IMG_H + gy) * IMG_W + gx] * KSC;
            p.z = base[(2 * IMG_H + gy) * IMG_W + gx] * KSC;
            p.w = 0.0f;
            smv[idx] = p;
        }
        __syncthreads();

        // Per-lane masked column weights: 2*g1d[l]*INVN/KD if partner col in-image.
        const int x0 = bx + tx;
        float glm[KS];
        #pragma unroll
        for (int l = 0; l < KS; ++l)
            glm[l] = ((unsigned)(x0 + l - FR) < (unsigned)IMG_W) ? (float)(g1d[l] * WPAIR) : 0.0f;

        const int r0 = ty * PPT;             // strip's first pixel row in tile
        // Thread window base: halo row r0, halo col tx. All tap offsets are
        // compile-time immediates from here ( (row*HX + col)*16 bytes <= 4.6KB ).
        const float4* wbase = &smv[r0 * HX + tx];

        float acc0 = 0.0f, acc1 = 0.0f;
        #pragma unroll
        for (int i = 0; i < PPT; ++i) {
            const float4 c = wbase[(i + FR) * HX + FR];   // center pixel (w=0)
            float accp = 0.0f;
            #pragma unroll
            for (int k = 0; k <= FR; ++k) {               // dy = k-3 in [-3,0]
                const int lmax = (k == FR) ? FR : KS;     // dy==0: left cols only
                // Row factor: g1d[k] if partner row in-image (top rows only fail).
                const float rw = (by + r0 + i + k >= FR) ? (float)g1d[k] : 0.0f;
                float t = 0.0f;
                #pragma unroll
                for (int l = 0; l < KS; ++l) {
                    if (l >= lmax) continue;              // compile-time
                    const float4 v = wbase[(i + k) * HX + l];  // ONE ds_read_b128
                    float d0 = c.x - v.x;
                    float d1 = c.y - v.y;
                    float d2 = c.z - v.z;
                    float d3 = c.w - v.w;                 // exactly 0
                    float s = d0 * d0;
                    s = fmaf(d1, d1, s);
                    s = fmaf(d2, d2, s);
                    s = fmaf(d3, d3, s);                  // adds exact 0; keeps b128 whole
                    float e = __builtin_amdgcn_exp2f(-s);
                    float sa = fabsf(d0) + fabsf(d1);
                    sa += fabsf(d2);
                    t = fmaf(sa, e * glm[l], t);
                }
                accp = fmaf(t, rw, accp);
            }
            if (i == 0) acc0 = accp; else acc1 = accp;
        }
        a = acc0 + acc1;
    } else {
        // ---- rim path: taps whose partner is out-of-image, counted once ----
        const int idx = blockIdx.x * 256 + tid;
        if (idx < NRIM_THREADS) {
            const int b = idx / RIM_PER_IMG;
            int r = idx - b * RIM_PER_IMG;
            int y, x;
            if (r < 3 * IMG_W) { y = r >> 9; x = r & (IMG_W - 1); }
            else if (r < 6 * IMG_W) { r -= 3 * IMG_W; y = (IMG_H - 3) + (r >> 9); x = r & (IMG_W - 1); }
            else if (r < 6 * IMG_W + 3 * (IMG_H - 6)) { r -= 6 * IMG_W; y = 3 + r / 3; x = r - 3 * (r / 3); }
            else { r -= 6 * IMG_W + 3 * (IMG_H - 6); y = 3 + r / 3; x = (IMG_W - 3) + (r - 3 * (r / 3)); }

            const float* base = in + (size_t)b * NC * IMG_H * IMG_W;
            const float cc0 = base[(0 * IMG_H + y) * IMG_W + x];
            const float cc1 = base[(1 * IMG_H + y) * IMG_W + x];
            const float cc2 = base[(2 * IMG_H + y) * IMG_W + x];

            #pragma unroll
            for (int k = 0; k < KS; ++k) {
                #pragma unroll
                for (int l = 0; l < KS; ++l) {
                    if (k == FR && l == FR) continue;
                    int qy = y + k - FR, qx = x + l - FR;
                    bool oob = ((unsigned)qy >= (unsigned)IMG_H) | ((unsigned)qx >= (unsigned)IMG_W);
                    if (oob) {
                        int ry = refl(qy, IMG_H), rx = refl(qx, IMG_W);
                        float v0 = base[(0 * IMG_H + ry) * IMG_W + rx];
                        float v1 = base[(1 * IMG_H + ry) * IMG_W + rx];
                        float v2 = base[(2 * IMG_H + ry) * IMG_W + rx];
                        float d0 = cc0 - v0, d1 = cc1 - v1, d2 = cc2 - v2;
                        float s = d0 * d0;
                        s = fmaf(d1, d1, s);
                        s = fmaf(d2, d2, s);
                        float e = __builtin_amdgcn_exp2f(-(K2F * s));
                        float sa = fabsf(d0) + fabsf(d1) + fabsf(d2);
                        a = fmaf(sa, e * (float)(g1d[k] * g1d[l] * INVN), a);
                    }
                }
            }
        }
        __syncthreads();
    }

    // Block reduction -> one partial per block.
    #pragma unroll
    for (int off = 32; off > 0; off >>= 1)
        a += __shfl_down(a, off, 64);
    if ((tid & 63) == 0) wsum[tid >> 6] = a;
    __syncthreads();
    if (tid == 0)
        partial[blockIdx.x] = wsum[0] + wsum[1] + wsum[2] + wsum[3];
}

__global__ __launch_bounds__(256) void finalize_kernel(const float* __restrict__ partial,
                                                       float* __restrict__ out) {
    __shared__ float wsum[4];
    const int tid = threadIdx.x;
    float a = 0.0f;
    for (int i = tid; i < NPART; i += 256) a += partial[i];
    #pragma unroll
    for (int off = 32; off > 0; off >>= 1)
        a += __shfl_down(a, off, 64);
    if ((tid & 63) == 0) wsum[tid >> 6] = a;
    __syncthreads();
    if (tid == 0)
        out[0] = (wsum[0] + wsum[1] + wsum[2] + wsum[3]) / (float)(NB * NC * IMG_H * IMG_W);
}

extern "C" void kernel_launch(void* const* d_in, const int* in_sizes, int n_in,
                              void* d_out, int out_size, void* d_ws, size_t ws_size,
                              hipStream_t stream) {
    const float* in = (const float*)d_in[0];
    float* out = (float*)d_out;
    float* ws  = (float*)d_ws;      // NPART partials; every slot written each call

    blt_fused<<<NBLK_A, 256, 0, stream>>>(in, ws);
    finalize_kernel<<<1, 256, 0, stream>>>(ws, out);
}

// Round 9
// 90.908 us; speedup vs baseline: 1.0604x; 1.0604x over previous
//
#include <hip/hip_runtime.h>

#define FR 3
#define KS 7
#define TLX 64
#define TLY 16
#define HX (TLX + 2*FR)       // 70
#define HY (TLY + FR)         // 19 (top halo only; half-kernel has dy<=0)
#define LSTR 72               // LDS row stride (floats)
#define IMG_H 512
#define IMG_W 512
#define NB 8
#define NC 3
#define GXB (IMG_W / TLX)     // 8
#define GYB (IMG_H / TLY)     // 32
#define NMAIN (GXB * GYB * NB)    // 2048
#define RIM_PER_IMG 6108          // 512^2 - 506^2
#define NRIM_THREADS (RIM_PER_IMG * NB)          // 48864
#define NRIM_BLK ((NRIM_THREADS + 255) / 256)    // 191
#define NBLK_A (NMAIN + NRIM_BLK)                // 2239
#define NPART NBLK_A

// exp(-50*s) = 2^(-K2*s), K2 = 50*log2(e)=72.13475204444817. Main kernel
// pre-scales inputs by K=sqrt(K2) so exp2 arg is just -(sum of squared diffs).
#define KSC 8.493218f
#define K2F 72.134752f

constexpr double g1d[KS] = {0.011108996538242306, 0.1353352832366127,
                            0.6065306597126334,   1.0,
                            0.6065306597126334,   0.1353352832366127,
                            0.011108996538242306};
constexpr double SUMG = 1.0 + 2.0 * (0.011108996538242306 + 0.1353352832366127
                                     + 0.6065306597126334);
constexpr double INVN = 1.0 / (SUMG * SUMG);
constexpr double KD   = 8.493218;   // must match KSC
constexpr double WPAIR = 2.0 * INVN / KD;   // pair-doubled, un-scaled, normalized

__device__ __forceinline__ int refl(int i, int n) {
    i = (i < 0) ? -i : i;
    return (i >= n) ? (2*n - 2 - i) : i;
}

// Fused kernel. Blocks [0, NRIM_BLK) = rim path (latency-bound, scheduled
// first); blocks [NRIM_BLK, NBLK_A) = main path.
// Main path splits per-block (wave-uniform) into:
//   interior tiles (~73%): per-tap weight is a compile-time LITERAL folded
//     into one v_mul — no mask arrays, no t/rw layer, single accumulator;
//     11 VALU + 1 exp per tap, scalar math (no v2f emulation movs).
//   border tiles: masked-weight path (R7 logic, scalarized).
__global__ __launch_bounds__(256) void blt_fused(const float* __restrict__ in,
                                                 float* __restrict__ partial) {
    __shared__ float sm[NC][HY][LSTR];   // 3*19*72*4 = 16416 B -> 8 blocks/CU
    __shared__ float wsum[4];
    const int tid = threadIdx.x;
    float a = 0.0f;

    if (blockIdx.x >= NRIM_BLK) {
        // ---- main path ----
        const int bid = blockIdx.x - NRIM_BLK;
        const int b   = bid >> 8;            // 256 blocks per image (8 x 32)
        const int rem = bid & 255;
        const int byi = rem >> 3;            // 0..31
        const int bxi = rem & 7;             // 0..7
        const int by  = byi * TLY;
        const int bx  = bxi * TLX;
        const int tx  = tid & 31;            // pair-column 0..31
        const int ty  = tid >> 5;            // 0..7 -> 2-row strip
        const float* base = in + (size_t)b * NC * IMG_H * IMG_W;

        // Stage reflect-padded halo tile (top+side), pre-scaled by K.
        for (int idx = tid; idx < HY * HX; idx += 256) {
            int ly = idx / HX;
            int lx = idx - ly * HX;
            int gy = refl(by + ly - FR, IMG_H);
            int gx = refl(bx + lx - FR, IMG_W);
            #pragma unroll
            for (int c = 0; c < NC; ++c)
                sm[c][ly][lx] = base[(c * IMG_H + gy) * IMG_W + gx] * KSC;
        }
        __syncthreads();

        const int r0 = ty * 2;               // strip's first pixel row in tile
        float cc[NC][2][2];                  // centers [ch][row i][col j]

        if ((bxi != 0) & (bxi != GXB - 1) & (byi != 0)) {
            // ================= interior fast path =================
            #pragma unroll
            for (int rr = 4; rr >= 0; --rr) {        // descending: centers first
                float w[NC][8];
                #pragma unroll
                for (int c = 0; c < NC; ++c) {
                    const float2* rp = reinterpret_cast<const float2*>(&sm[c][r0 + rr][2 * tx]);
                    float2 p0 = rp[0], p1 = rp[1], p2 = rp[2], p3 = rp[3];
                    w[c][0] = p0.x; w[c][1] = p0.y; w[c][2] = p1.x; w[c][3] = p1.y;
                    w[c][4] = p2.x; w[c][5] = p2.y; w[c][6] = p3.x; w[c][7] = p3.y;
                }
                #pragma unroll
                for (int i = 0; i < 2; ++i) {
                    const int k = rr - i;            // dy + 3
                    if (k < 0 || k > FR) continue;   // compile-time
                    if (k == FR) {                   // center row: capture centers
                        #pragma unroll
                        for (int c = 0; c < NC; ++c) {
                            cc[c][i][0] = w[c][3];
                            cc[c][i][1] = w[c][4];
                        }
                    }
                    const int lmax = (k == FR) ? FR : KS;   // dy==0: left cols only
                    #pragma unroll
                    for (int j = 0; j < 2; ++j) {
                        #pragma unroll
                        for (int l = 0; l < KS; ++l) {
                            if (l >= lmax) continue;        // compile-time
                            float d0 = cc[0][i][j] - w[0][l + j];
                            float d1 = cc[1][i][j] - w[1][l + j];
                            float d2 = cc[2][i][j] - w[2][l + j];
                            float s = d0 * d0;
                            s = fmaf(d1, d1, s);
                            s = fmaf(d2, d2, s);
                            float e = __builtin_amdgcn_exp2f(-s);
                            float sa = fabsf(d0) + fabsf(d1);
                            sa += fabsf(d2);
                            // weight is a compile-time literal: no registers
                            a = fmaf(sa, e * (float)(g1d[k] * g1d[l] * WPAIR), a);
                        }
                    }
                }
            }
        } else {
            // ================= border masked path =================
            const int x0 = bx + 2 * tx;
            float glm0[KS], glm1[KS];
            #pragma unroll
            for (int l = 0; l < KS; ++l) {
                glm0[l] = ((unsigned)(x0 + l - FR)     < (unsigned)IMG_W) ? (float)(g1d[l] * WPAIR) : 0.0f;
                glm1[l] = ((unsigned)(x0 + 1 + l - FR) < (unsigned)IMG_W) ? (float)(g1d[l] * WPAIR) : 0.0f;
            }
            #pragma unroll
            for (int rr = 4; rr >= 0; --rr) {
                float w[NC][8];
                #pragma unroll
                for (int c = 0; c < NC; ++c) {
                    const float2* rp = reinterpret_cast<const float2*>(&sm[c][r0 + rr][2 * tx]);
                    float2 p0 = rp[0], p1 = rp[1], p2 = rp[2], p3 = rp[3];
                    w[c][0] = p0.x; w[c][1] = p0.y; w[c][2] = p1.x; w[c][3] = p1.y;
                    w[c][4] = p2.x; w[c][5] = p2.y; w[c][6] = p3.x; w[c][7] = p3.y;
                }
                #pragma unroll
                for (int i = 0; i < 2; ++i) {
                    const int k = rr - i;
                    if (k < 0 || k > FR) continue;
                    if (k == FR) {
                        #pragma unroll
                        for (int c = 0; c < NC; ++c) {
                            cc[c][i][0] = w[c][3];
                            cc[c][i][1] = w[c][4];
                        }
                    }
                    const int lmax = (k == FR) ? FR : KS;
                    // Row factor: g1d[k] if partner row in-image (top rows fail).
                    const float rw = (by + r0 + rr >= FR) ? (float)g1d[k] : 0.0f;
                    float t0 = 0.0f, t1 = 0.0f;
                    #pragma unroll
                    for (int l = 0; l < KS; ++l) {
                        if (l >= lmax) continue;
                        {   // j = 0
                            float d0 = cc[0][i][0] - w[0][l];
                            float d1 = cc[1][i][0] - w[1][l];
                            float d2 = cc[2][i][0] - w[2][l];
                            float s = d0 * d0;
                            s = fmaf(d1, d1, s);
                            s = fmaf(d2, d2, s);
                            float e = __builtin_amdgcn_exp2f(-s);
                            float sa = fabsf(d0) + fabsf(d1);
                            sa += fabsf(d2);
                            t0 = fmaf(sa, e * glm0[l], t0);
                        }
                        {   // j = 1
                            float d0 = cc[0][i][1] - w[0][l + 1];
                            float d1 = cc[1][i][1] - w[1][l + 1];
                            float d2 = cc[2][i][1] - w[2][l + 1];
                            float s = d0 * d0;
                            s = fmaf(d1, d1, s);
                            s = fmaf(d2, d2, s);
                            float e = __builtin_amdgcn_exp2f(-s);
                            float sa = fabsf(d0) + fabsf(d1);
                            sa += fabsf(d2);
                            t1 = fmaf(sa, e * glm1[l], t1);
                        }
                    }
                    a = fmaf(t0, rw, a);
                    a = fmaf(t1, rw, a);
                }
            }
        }
    } else {
        // ---- rim path: taps whose partner is out-of-image, counted once ----
        const int idx = blockIdx.x * 256 + tid;
        if (idx < NRIM_THREADS) {
            const int b = idx / RIM_PER_IMG;
            int r = idx - b * RIM_PER_IMG;
            int y, x;
            if (r < 3 * IMG_W) { y = r >> 9; x = r & (IMG_W - 1); }
            else if (r < 6 * IMG_W) { r -= 3 * IMG_W; y = (IMG_H - 3) + (r >> 9); x = r & (IMG_W - 1); }
            else if (r < 6 * IMG_W + 3 * (IMG_H - 6)) { r -= 6 * IMG_W; y = 3 + r / 3; x = r - 3 * (r / 3); }
            else { r -= 6 * IMG_W + 3 * (IMG_H - 6); y = 3 + r / 3; x = (IMG_W - 3) + (r - 3 * (r / 3)); }

            const float* base = in + (size_t)b * NC * IMG_H * IMG_W;
            const float cc0 = base[(0 * IMG_H + y) * IMG_W + x];
            const float cc1 = base[(1 * IMG_H + y) * IMG_W + x];
            const float cc2 = base[(2 * IMG_H + y) * IMG_W + x];

            #pragma unroll
            for (int k = 0; k < KS; ++k) {
                #pragma unroll
                for (int l = 0; l < KS; ++l) {
                    if (k == FR && l == FR) continue;
                    int qy = y + k - FR, qx = x + l - FR;
                    bool oob = ((unsigned)qy >= (unsigned)IMG_H) | ((unsigned)qx >= (unsigned)IMG_W);
                    if (oob) {
                        int ry = refl(qy, IMG_H), rx = refl(qx, IMG_W);
                        float v0 = base[(0 * IMG_H + ry) * IMG_W + rx];
                        float v1 = base[(1 * IMG_H + ry) * IMG_W + rx];
                        float v2 = base[(2 * IMG_H + ry) * IMG_W + rx];
                        float d0 = cc0 - v0, d1 = cc1 - v1, d2 = cc2 - v2;
                        float s = d0 * d0;
                        s = fmaf(d1, d1, s);
                        s = fmaf(d2, d2, s);
                        float e = __builtin_amdgcn_exp2f(-(K2F * s));
                        float sa = fabsf(d0) + fabsf(d1) + fabsf(d2);
                        a = fmaf(sa, e * (float)(g1d[k] * g1d[l] * INVN), a);
                    }
                }
            }
        }
        __syncthreads();
    }

    // Block reduction -> one partial per block.
    #pragma unroll
    for (int off = 32; off > 0; off >>= 1)
        a += __shfl_down(a, off, 64);
    if ((tid & 63) == 0) wsum[tid >> 6] = a;
    __syncthreads();
    if (tid == 0)
        partial[blockIdx.x] = wsum[0] + wsum[1] + wsum[2] + wsum[3];
}

__global__ __launch_bounds__(256) void finalize_kernel(const float* __restrict__ partial,
                                                       float* __restrict__ out) {
    __shared__ float wsum[4];
    const int tid = threadIdx.x;
    float a = 0.0f;
    for (int i = tid; i < NPART; i += 256) a += partial[i];
    #pragma unroll
    for (int off = 32; off > 0; off >>= 1)
        a += __shfl_down(a, off, 64);
    if ((tid & 63) == 0) wsum[tid >> 6] = a;
    __syncthreads();
    if (tid == 0)
        out[0] = (wsum[0] + wsum[1] + wsum[2] + wsum[3]) / (float)(NB * NC * IMG_H * IMG_W);
}

extern "C" void kernel_launch(void* const* d_in, const int* in_sizes, int n_in,
                              void* d_out, int out_size, void* d_ws, size_t ws_size,
                              hipStream_t stream) {
    const float* in = (const float*)d_in[0];
    float* out = (float*)d_out;
    float* ws  = (float*)d_ws;      // NPART partials; every slot written each call

    blt_fused<<<NBLK_A, 256, 0, stream>>>(in, ws);
    finalize_kernel<<<1, 256, 0, stream>>>(ws, out);
}